// Round 8
// baseline (5189.399 us; speedup 1.0000x reference)
//
#include <hip/hip_runtime.h>
#include <cstdint>

typedef unsigned long long u64;
typedef float v2f __attribute__((ext_vector_type(2)));

static constexpr int BB = 2;
static constexpr int NN = 16384;
static constexpr int SS = 4096;

// one step of a u64 max-combine via DPP (CTRL is a DPP control immediate)
template <int CTRL>
__device__ __forceinline__ u64 dpp_max_step(u64 k) {
  int lo = (int)(unsigned)(k & 0xffffffffull);
  int hi = (int)(unsigned)(k >> 32);
  int slo = __builtin_amdgcn_update_dpp(0, lo, CTRL, 0xF, 0xF, true);
  int shi = __builtin_amdgcn_update_dpp(0, hi, CTRL, 0xF, 0xF, true);
  u64 o = ((u64)(unsigned)shi << 32) | (u64)(unsigned)slo;
  return (o > k) ? o : k;
}

// u32 max-reduce across the wave (prefix to lane63 via DPP), broadcast to all
// lanes through readlane. Values must be >= 0-safe (identity 0).
__device__ __forceinline__ unsigned wave_umax_bcast(unsigned v) {
  unsigned o;
#define WSTEP(C)                                                              \
  o = (unsigned)__builtin_amdgcn_update_dpp(0, (int)v, C, 0xF, 0xF, true);   \
  v = (o > v) ? o : v;
  WSTEP(0x111)  // row_shr:1
  WSTEP(0x112)  // row_shr:2
  WSTEP(0x114)  // row_shr:4
  WSTEP(0x118)  // row_shr:8
  WSTEP(0x142)  // row_bcast:15
  WSTEP(0x143)  // row_bcast:31
#undef WSTEP
  return (unsigned)__builtin_amdgcn_readlane((int)v, 63);
}

__device__ __forceinline__ v2f emin2(v2f a, v2f b) {
  v2f r; r[0] = fminf(a[0], b[0]); r[1] = fminf(a[1], b[1]); return r;
}
__device__ __forceinline__ v2f emax2(v2f a, v2f b) {
  v2f r; r[0] = fmaxf(a[0], b[0]); r[1] = fmaxf(a[1], b[1]); return r;
}

// spread 4 bits: bit k -> bit 3k (for 12-bit Morton)
__device__ __forceinline__ unsigned spread4(unsigned v) {
  return (v & 1u) | ((v & 2u) << 2) | ((v & 4u) << 4) | ((v & 8u) << 6);
}

__device__ __forceinline__ unsigned cell_of(float x, float y, float z) {
  int cx = (int)floorf((x + 4.f) * 2.f);
  int cy = (int)floorf((y + 4.f) * 2.f);
  int cz = (int)floorf((z + 4.f) * 2.f);
  cx = min(max(cx, 0), 15); cy = min(max(cy, 0), 15); cz = min(max(cz, 0), 15);
  return spread4((unsigned)cx) | (spread4((unsigned)cy) << 1) |
         (spread4((unsigned)cz) << 2);
}

// ---------------------------------------------------------------------------
// Counting sort by 12-bit Morton cell -> float4 {x,y,z,bits(orig_idx)}.
// Within-cell order is atomic-nondeterministic but the FPS output is
// invariant to it (keys carry original indices; skips are provable no-ops).
// ---------------------------------------------------------------------------
__global__ __launch_bounds__(1024) void sort_kernel(
    const float* __restrict__ xyz, float4* __restrict__ spts)
{
  const int b = blockIdx.x;
  const float* X = xyz + (size_t)b * NN * 3;
  float4* SP = spts + (size_t)b * NN;
  const int t = threadIdx.x;
  const int lane = t & 63, wid = t >> 6;

  __shared__ unsigned h[4096];
  __shared__ unsigned wtot[16];
  for (int j = t; j < 4096; j += 1024) h[j] = 0;
  __syncthreads();

  for (int i = 0; i < 16; ++i) {
    int p = i * 1024 + t;
    atomicAdd(&h[cell_of(X[p * 3 + 0], X[p * 3 + 1], X[p * 3 + 2])], 1u);
  }
  __syncthreads();

  unsigned a0 = h[4 * t], a1 = h[4 * t + 1], a2 = h[4 * t + 2], a3 = h[4 * t + 3];
  unsigned s4 = a0 + a1 + a2 + a3;
  unsigned incl = s4;
  for (int off = 1; off < 64; off <<= 1) {
    unsigned v = (unsigned)__shfl_up((int)incl, off);
    if (lane >= off) incl += v;
  }
  if (lane == 63) wtot[wid] = incl;
  __syncthreads();
  if (t == 0) {
    unsigned run = 0;
    for (int j = 0; j < 16; ++j) { unsigned tm = wtot[j]; wtot[j] = run; run += tm; }
  }
  __syncthreads();
  unsigned ex = wtot[wid] + (incl - s4);
  h[4 * t] = ex; h[4 * t + 1] = ex + a0;
  h[4 * t + 2] = ex + a0 + a1; h[4 * t + 3] = ex + a0 + a1 + a2;
  __syncthreads();

  for (int i = 0; i < 16; ++i) {
    int p = i * 1024 + t;
    float x = X[p * 3 + 0], y = X[p * 3 + 1], z = X[p * 3 + 2];
    unsigned pos = atomicAdd(&h[cell_of(x, y, z)], 1u);
    SP[pos] = make_float4(x, y, z, __int_as_float(p));
  }
}

// ---------------------------------------------------------------------------
// FPS: 8 waves x 32 pts/thread, packed-f32 updates, 256-pt exact pruning.
// Wave w owns sorted points [w*2048, (w+1)*2048). Scalar slot s of lane L =
// point w*2048 + s*64 + L; v2f slot v packs scalar slots {2v, 2v+1}; sub J
// (J=0..7) = v2f slots {2J, 2J+1} = a CONTIGUOUS 256-point run.
// Exactness: dist = ((dx*dx + dy*dy) + dz*dz) per element with fp contract
// OFF (packed ops round identically to scalar); dist>=0 so float-bit compare
// == float compare; block argmax key = (dist_bits<<32)|~orig_idx (numpy
// first-index tie-break, invariant to sort nondeterminism). Sub skip when
// lb2*(1-2^-16) >= cached sub max -> every suppressed fmin is provably a
// no-op under both our and the reference's rounding.
// Per iter: lane tests sub lane&7's bbox -> ballot -> <=8 wave-uniform
// register-only sub updates (u32-bit max reduce + tie-exact extraction),
// cross-sub u64 DPP ror, one barrier, cross-wave u64 DPP ror -> sel.
// ---------------------------------------------------------------------------
__global__ __launch_bounds__(512, 2) void fps_kernel(
    const float* __restrict__ xyz, const float4* __restrict__ spts,
    float* __restrict__ new_xyz)
{
#pragma clang fp contract(off)
  const int b = blockIdx.x;
  const float* X = xyz + (size_t)b * NN * 3;
  float* NX = new_xyz + (size_t)b * SS * 3;
  const float4* SP = spts + (size_t)b * NN;
  const int t = threadIdx.x;
  const int lane = t & 63, wid = t >> 6;
  const float4* WP = SP + wid * 2048;

  v2f xp0, xp1, xp2, xp3, xp4, xp5, xp6, xp7,
      xp8, xp9, xp10, xp11, xp12, xp13, xp14, xp15;
  v2f yp0, yp1, yp2, yp3, yp4, yp5, yp6, yp7,
      yp8, yp9, yp10, yp11, yp12, yp13, yp14, yp15;
  v2f zp0, zp1, zp2, zp3, zp4, zp5, zp6, zp7,
      zp8, zp9, zp10, zp11, zp12, zp13, zp14, zp15;
  v2f dp0, dp1, dp2, dp3, dp4, dp5, dp6, dp7,
      dp8, dp9, dp10, dp11, dp12, dp13, dp14, dp15;
  unsigned na0, na1, na2, na3, na4, na5, na6, na7,
           na8, na9, na10, na11, na12, na13, na14, na15;
  unsigned nb0, nb1, nb2, nb3, nb4, nb5, nb6, nb7,
           nb8, nb9, nb10, nb11, nb12, nb13, nb14, nb15;

#define LOADV(v)                                                              \
  {                                                                           \
    float4 Pa = WP[(2 * (v)) * 64 + lane];                                    \
    float4 Pb = WP[(2 * (v) + 1) * 64 + lane];                                \
    xp##v[0] = Pa.x; xp##v[1] = Pb.x;                                         \
    yp##v[0] = Pa.y; yp##v[1] = Pb.y;                                         \
    zp##v[0] = Pa.z; zp##v[1] = Pb.z;                                         \
    na##v = ~__float_as_uint(Pa.w); nb##v = ~__float_as_uint(Pb.w);           \
    dp##v[0] = 1e10f; dp##v[1] = 1e10f;                                       \
  }
  LOADV(0)  LOADV(1)  LOADV(2)  LOADV(3)
  LOADV(4)  LOADV(5)  LOADV(6)  LOADV(7)
  LOADV(8)  LOADV(9)  LOADV(10) LOADV(11)
  LOADV(12) LOADV(13) LOADV(14) LOADV(15)
#undef LOADV

  // bbox of sub lane&7 (one sub's bbox kept per lane, 6 registers)
  float bnx = 0.f, bny = 0.f, bnz = 0.f, bxx = 0.f, bxy = 0.f, bxz = 0.f;
#define SUBBOX(J, A, B)                                                       \
  {                                                                           \
    v2f nv = emin2(xp##A, xp##B), xv = emax2(xp##A, xp##B);                   \
    float mnx = fminf(nv[0], nv[1]), mxx = fmaxf(xv[0], xv[1]);               \
    nv = emin2(yp##A, yp##B); xv = emax2(yp##A, yp##B);                       \
    float mny = fminf(nv[0], nv[1]), mxy = fmaxf(xv[0], xv[1]);               \
    nv = emin2(zp##A, zp##B); xv = emax2(zp##A, zp##B);                       \
    float mnz = fminf(nv[0], nv[1]), mxz = fmaxf(xv[0], xv[1]);               \
    for (int off = 1; off < 64; off <<= 1) {                                  \
      mnx = fminf(mnx, __shfl_xor(mnx, off));                                 \
      mxx = fmaxf(mxx, __shfl_xor(mxx, off));                                 \
      mny = fminf(mny, __shfl_xor(mny, off));                                 \
      mxy = fmaxf(mxy, __shfl_xor(mxy, off));                                 \
      mnz = fminf(mnz, __shfl_xor(mnz, off));                                 \
      mxz = fmaxf(mxz, __shfl_xor(mxz, off));                                 \
    }                                                                         \
    if ((lane & 7) == J) { bnx = mnx; bny = mny; bnz = mnz;                   \
                           bxx = mxx; bxy = mxy; bxz = mxz; }                 \
  }
  SUBBOX(0, 0, 1)   SUBBOX(1, 2, 3)   SUBBOX(2, 4, 5)   SUBBOX(3, 6, 7)
  SUBBOX(4, 8, 9)   SUBBOX(5, 10, 11) SUBBOX(6, 12, 13) SUBBOX(7, 14, 15)
#undef SUBBOX

  // cached exact key of sub lane&7: hi = max-dist bits, lo = ~orig_idx
  unsigned wkhi = __float_as_uint(1e10f), wklo = 0u;

  __shared__ u64 s_part[2][8];
  int sel = 0;

  for (int it = 1; it < SS; ++it) {
    const float qx = X[sel * 3 + 0];
    const float qy = X[sel * 3 + 1];
    const float qz = X[sel * 3 + 2];
    if (t == 0) {
      NX[(it - 1) * 3 + 0] = qx;
      NX[(it - 1) * 3 + 1] = qy;
      NX[(it - 1) * 3 + 2] = qz;
    }
    v2f q2x, q2y, q2z;
    q2x[0] = qx; q2x[1] = qx;
    q2y[0] = qy; q2y[1] = qy;
    q2z[0] = qz; q2z[1] = qz;

    // conservative lower bound of dist^2(q, my sub's bbox)
    float tx = fmaxf(fmaxf(__fsub_rn(bnx, qx), __fsub_rn(qx, bxx)), 0.f);
    float ty = fmaxf(fmaxf(__fsub_rn(bny, qy), __fsub_rn(qy, bxy)), 0.f);
    float tz = fmaxf(fmaxf(__fsub_rn(bnz, qz), __fsub_rn(qz, bxz)), 0.f);
    float lb2 = fmaf(tx, tx, fmaf(ty, ty, __fmul_rn(tz, tz)));
    u64 bm = __ballot(__fmul_rn(lb2, 0.99998474f) < __uint_as_float(wkhi));
    unsigned m = (unsigned)bm & 0xFFu;  // lanes 0..7 = subs 0..7 (uniform)

#define SUBUPD(J, A, B)                                                       \
    if (m & (1u << J)) {                                                      \
      v2f dxA = xp##A - q2x, dyA = yp##A - q2y, dzA = zp##A - q2z;            \
      v2f sA = (dxA * dxA + dyA * dyA) + dzA * dzA;                           \
      dp##A = emin2(dp##A, sA);                                               \
      v2f dxB = xp##B - q2x, dyB = yp##B - q2y, dzB = zp##B - q2z;            \
      v2f sB = (dxB * dxB + dyB * dyB) + dzB * dzB;                           \
      dp##B = emin2(dp##B, sB);                                               \
      v2f mv = emax2(dp##A, dp##B);                                           \
      unsigned mm = __float_as_uint(fmaxf(mv[0], mv[1]));                     \
      mm = wave_umax_bcast(mm);                                               \
      unsigned c0 = (__float_as_uint(dp##A[0]) == mm) ? na##A : 0u;           \
      unsigned c1 = (__float_as_uint(dp##A[1]) == mm) ? nb##A : 0u;           \
      unsigned c2 = (__float_as_uint(dp##B[0]) == mm) ? na##B : 0u;           \
      unsigned c3 = (__float_as_uint(dp##B[1]) == mm) ? nb##B : 0u;           \
      unsigned cc = wave_umax_bcast(max(max(c0, c1), max(c2, c3)));           \
      if ((lane & 7) == J) { wkhi = mm; wklo = cc; }                          \
    }
    SUBUPD(0, 0, 1)   SUBUPD(1, 2, 3)   SUBUPD(2, 4, 5)   SUBUPD(3, 6, 7)
    SUBUPD(4, 8, 9)   SUBUPD(5, 10, 11) SUBUPD(6, 12, 13) SUBUPD(7, 14, 15)
#undef SUBUPD

    // wave key = max over the 8 sub keys (replicated across lanes by &7)
    u64 kw = ((u64)wkhi << 32) | (u64)wklo;
    kw = dpp_max_step<0x124>(kw);  // row_ror:4
    kw = dpp_max_step<0x122>(kw);  // row_ror:2
    kw = dpp_max_step<0x121>(kw);  // row_ror:1

    const int pb = it & 1;
    if (lane == 0) s_part[pb][wid] = kw;
    __syncthreads();
    u64 kk = s_part[pb][lane & 7];
    kk = dpp_max_step<0x124>(kk);  // row_ror:4
    kk = dpp_max_step<0x122>(kk);  // row_ror:2
    kk = dpp_max_step<0x121>(kk);  // row_ror:1
    sel = (int)(~(unsigned)(kk & 0xffffffffull));
    sel = __builtin_amdgcn_readfirstlane(sel);
  }
  if (t == 0) {
    NX[(SS - 1) * 3 + 0] = X[sel * 3 + 0];
    NX[(SS - 1) * 3 + 1] = X[sel * 3 + 1];
    NX[(SS - 1) * 3 + 2] = X[sel * 3 + 2];
  }
}

// ---------------------------------------------------------------------------
// Ball query: one 64-lane wave per query point. Emits the first NS in-radius
// point indices in ascending order (matches reference top_k(-keys) trick),
// pads with the first hit.
// ---------------------------------------------------------------------------
template <int NS>
__global__ __launch_bounds__(256) void ballq_kernel(
    const float* __restrict__ xyz, const float* __restrict__ new_xyz,
    int* __restrict__ out, float r2)
{
  const int q = blockIdx.x * 4 + (threadIdx.x >> 6);
  const int lane = threadIdx.x & 63;
  const int b = q >> 12;  // q / SS
  const float* X = xyz + (size_t)b * NN * 3;
  const float cx = new_xyz[q * 3 + 0];
  const float cy = new_xyz[q * 3 + 1];
  const float cz = new_xyz[q * 3 + 2];
  int* o = out + (size_t)q * NS;
  int base = 0;
  int firstIdx = 0x7fffffff;
  for (int c0 = 0; c0 < NN; c0 += 64) {
    const int p = c0 + lane;
    float dx = __fsub_rn(cx, X[p * 3 + 0]);
    float dy = __fsub_rn(cy, X[p * 3 + 1]);
    float dz = __fsub_rn(cz, X[p * 3 + 2]);
    float d2 = __fadd_rn(__fadd_rn(__fmul_rn(dx, dx), __fmul_rn(dy, dy)),
                         __fmul_rn(dz, dz));
    const bool inb = d2 < r2;
    const unsigned long long mm = __ballot(inb);
    if (inb) {
      int rank = base + (int)__popcll(mm & ((1ull << lane) - 1ull));
      if (rank < NS) {
        o[rank] = p;
        if (rank == 0) firstIdx = p;
      }
    }
    base += (int)__popcll(mm);
    if (base >= NS) break;
  }
#pragma unroll
  for (int off = 32; off >= 1; off >>= 1)
    firstIdx = min(firstIdx, __shfl_xor(firstIdx, off));
  for (int r = base + lane; r < NS; r += 64) o[r] = firstIdx;
}

// ---------------------------------------------------------------------------
// Grouping + 3-layer MLP + max over samples. One thread per (query, sample).
// ---------------------------------------------------------------------------
template <int NS, int C1, int C2, int C3>
__global__ __launch_bounds__(256) void group_mlp_kernel(
    const float* __restrict__ xyz, const float* __restrict__ feat,
    const float* __restrict__ new_xyz, const int* __restrict__ idx,
    const float* __restrict__ w0, const float* __restrict__ b0,
    const float* __restrict__ w1, const float* __restrict__ b1,
    const float* __restrict__ w2, const float* __restrict__ b2,
    float* __restrict__ pf, int chOff)
{
  constexpr int QPB = 256 / NS;
  const int q = blockIdx.x * QPB + (int)(threadIdx.x / NS);
  const int k = (int)(threadIdx.x % NS);
  const int b = q >> 12;
  const int s = q & (SS - 1);
  const float* X = xyz + (size_t)b * NN * 3;
  const float* F = feat + (size_t)b * 6 * NN;
  const int p = idx[(size_t)q * NS + k];

  float in[9];
  in[0] = X[p * 3 + 0] - new_xyz[q * 3 + 0];
  in[1] = X[p * 3 + 1] - new_xyz[q * 3 + 1];
  in[2] = X[p * 3 + 2] - new_xyz[q * 3 + 2];
#pragma unroll
  for (int c = 0; c < 6; ++c) in[3 + c] = F[c * NN + p];

  float h1[C1];
#pragma unroll
  for (int oc = 0; oc < C1; ++oc) {
    float a = b0[oc];
#pragma unroll
    for (int c = 0; c < 9; ++c) a = fmaf(w0[oc * 9 + c], in[c], a);
    h1[oc] = fmaxf(a, 0.f);
  }
  float h2[C2];
#pragma unroll
  for (int oc = 0; oc < C2; ++oc) {
    float a = b1[oc];
#pragma unroll
    for (int c = 0; c < C1; ++c) a = fmaf(w1[oc * C1 + c], h1[c], a);
    h2[oc] = fmaxf(a, 0.f);
  }
#pragma unroll
  for (int oc = 0; oc < C3; ++oc) {
    float a = b2[oc];
#pragma unroll
    for (int c = 0; c < C2; ++c) a = fmaf(w2[oc * C2 + c], h2[c], a);
    float v = fmaxf(a, 0.f);
#pragma unroll
    for (int off = NS / 2; off >= 1; off >>= 1)
      v = fmaxf(v, __shfl_xor(v, off));
    if (k == 0) pf[(((size_t)b * 96) + chOff + oc) * SS + s] = v;
  }
}

// ---------------------------------------------------------------------------
// Image branch + attention + fusion, 32-column LDS tiles.
// ---------------------------------------------------------------------------
__global__ __launch_bounds__(256) void img_fuse_kernel(
    const float* __restrict__ imgf, const float* __restrict__ pf,
    const float* __restrict__ w_img, const float* __restrict__ b_img,
    const float* __restrict__ w_fc2, const float* __restrict__ b_fc2,
    const float* __restrict__ w_fc3, const float* __restrict__ b_fc3,
    const float* __restrict__ w_pc, const float* __restrict__ b_pc,
    const float* __restrict__ w_fuse, const float* __restrict__ b_fuse,
    float* __restrict__ out)
{
  constexpr int TS = 32;
  __shared__ float x_lds[64][TS];
  __shared__ float img_lds[96][TS];
  __shared__ float ri_lds[24][TS];
  __shared__ float att_lds[TS];
  __shared__ float imgn_lds[96][TS];
  __shared__ float pf_lds[96][TS];

  const int blk = blockIdx.x;            // B * (SS/TS) = 256 blocks
  const int b = blk / (SS / TS);
  const int s0 = (blk % (SS / TS)) * TS;
  const int tid = threadIdx.x;

  for (int i = tid; i < 64 * TS; i += 256) {
    int c = i / TS, s = i % TS;
    x_lds[c][s] = imgf[((size_t)b * 64 + c) * SS + s0 + s];
  }
  for (int i = tid; i < 96 * TS; i += 256) {
    int c = i / TS, s = i % TS;
    pf_lds[c][s] = pf[((size_t)b * 96 + c) * SS + s0 + s];
  }
  __syncthreads();

  for (int i = tid; i < 96 * TS; i += 256) {
    int oc = i / TS, s = i % TS;
    float a = b_img[oc];
#pragma unroll
    for (int c = 0; c < 64; ++c) a = fmaf(w_img[oc * 64 + c], x_lds[c][s], a);
    img_lds[oc][s] = fmaxf(a, 0.f);
  }
  __syncthreads();

  for (int i = tid; i < 24 * TS; i += 256) {
    int r = i / TS, s = i % TS;
    float a = b_fc2[r];
#pragma unroll
    for (int c = 0; c < 96; ++c) a = fmaf(w_fc2[r * 96 + c], img_lds[c][s], a);
    ri_lds[r][s] = tanhf(a);
  }
  __syncthreads();

  if (tid < TS) {
    float a = b_fc3[0];
#pragma unroll
    for (int r = 0; r < 24; ++r) a = fmaf(w_fc3[r], ri_lds[r][tid], a);
    att_lds[tid] = 1.f / (1.f + expf(-a));
  }
  __syncthreads();

  for (int i = tid; i < 96 * TS; i += 256) {
    int c = i / TS, s = i % TS;
    float v = img_lds[c][s];
    img_lds[c][s] = fmaf(v, att_lds[s], v);
  }
  __syncthreads();

  for (int i = tid; i < 96 * TS; i += 256) {
    int oc = i / TS, s = i % TS;
    float a = b_pc[oc];
#pragma unroll
    for (int c = 0; c < 96; ++c) a = fmaf(w_pc[oc * 96 + c], img_lds[c][s], a);
    imgn_lds[oc][s] = fmaxf(a, 0.f);
  }
  __syncthreads();

  for (int i = tid; i < 128 * TS; i += 256) {
    int oc = i / TS, s = i % TS;
    float a = b_fuse[oc];
#pragma unroll
    for (int c = 0; c < 96; ++c) a = fmaf(w_fuse[oc * 192 + c], pf_lds[c][s], a);
#pragma unroll
    for (int c = 0; c < 96; ++c) a = fmaf(w_fuse[oc * 192 + 96 + c], imgn_lds[c][s], a);
    out[((size_t)b * 128 + oc) * SS + s0 + s] = fmaxf(a, 0.f);
  }
}

// ---------------------------------------------------------------------------
extern "C" void kernel_launch(void* const* d_in, const int* in_sizes, int n_in,
                              void* d_out, int out_size, void* d_ws, size_t ws_size,
                              hipStream_t stream)
{
  const float* xyz    = (const float*)d_in[0];
  const float* feat   = (const float*)d_in[1];
  const float* imgf   = (const float*)d_in[2];
  const float* w0_0   = (const float*)d_in[3];
  const float* b0_0   = (const float*)d_in[4];
  const float* w0_1   = (const float*)d_in[5];
  const float* b0_1   = (const float*)d_in[6];
  const float* w0_2   = (const float*)d_in[7];
  const float* b0_2   = (const float*)d_in[8];
  const float* w1_0   = (const float*)d_in[9];
  const float* b1_0   = (const float*)d_in[10];
  const float* w1_1   = (const float*)d_in[11];
  const float* b1_1   = (const float*)d_in[12];
  const float* w1_2   = (const float*)d_in[13];
  const float* b1_2   = (const float*)d_in[14];
  const float* w_img  = (const float*)d_in[15];
  const float* b_img  = (const float*)d_in[16];
  const float* w_fc2  = (const float*)d_in[17];
  const float* b_fc2  = (const float*)d_in[18];
  const float* w_fc3  = (const float*)d_in[19];
  const float* b_fc3  = (const float*)d_in[20];
  const float* w_pc   = (const float*)d_in[21];
  const float* b_pc   = (const float*)d_in[22];
  const float* w_fuse = (const float*)d_in[23];
  const float* b_fuse = (const float*)d_in[24];
  float* out = (float*)d_out;

  float4* spts = (float4*)d_ws;                          // B*N float4
  float*  nxyz = (float*)(spts + (size_t)BB * NN);       // B*S*3 f32
  int*    idx0 = (int*)(nxyz + (size_t)BB * SS * 3);     // B*S*16 i32
  int*    idx1 = idx0 + (size_t)BB * SS * 16;            // B*S*32 i32
  float*  pf   = (float*)(idx1 + (size_t)BB * SS * 32);  // B*96*S f32

  sort_kernel<<<BB, 1024, 0, stream>>>(xyz, spts);
  fps_kernel<<<BB, 512, 0, stream>>>(xyz, spts, nxyz);
  ballq_kernel<16><<<BB * SS / 4, 256, 0, stream>>>(xyz, nxyz, idx0, 0.25f);
  ballq_kernel<32><<<BB * SS / 4, 256, 0, stream>>>(xyz, nxyz, idx1, 1.0f);
  group_mlp_kernel<16, 16, 16, 32><<<BB * SS / 16, 256, 0, stream>>>(
      xyz, feat, nxyz, idx0, w0_0, b0_0, w0_1, b0_1, w0_2, b0_2, pf, 0);
  group_mlp_kernel<32, 32, 32, 64><<<BB * SS / 8, 256, 0, stream>>>(
      xyz, feat, nxyz, idx1, w1_0, b1_0, w1_1, b1_1, w1_2, b1_2, pf, 32);
  img_fuse_kernel<<<BB * SS / 32, 256, 0, stream>>>(
      imgf, pf, w_img, b_img, w_fc2, b_fc2, w_fc3, b_fc3, w_pc, b_pc,
      w_fuse, b_fuse, out);
}

// Round 9
// 4213.570 us; speedup vs baseline: 1.2316x; 1.2316x over previous
//
#include <hip/hip_runtime.h>
#include <cstdint>

typedef unsigned long long u64;
typedef float v2f __attribute__((ext_vector_type(2)));

static constexpr int BB = 2;
static constexpr int NN = 16384;
static constexpr int SS = 4096;

// one step of a u64 max-combine via DPP (CTRL is a DPP control immediate)
template <int CTRL>
__device__ __forceinline__ u64 dpp_max_step(u64 k) {
  int lo = (int)(unsigned)(k & 0xffffffffull);
  int hi = (int)(unsigned)(k >> 32);
  int slo = __builtin_amdgcn_update_dpp(0, lo, CTRL, 0xF, 0xF, true);
  int shi = __builtin_amdgcn_update_dpp(0, hi, CTRL, 0xF, 0xF, true);
  u64 o = ((u64)(unsigned)shi << 32) | (u64)(unsigned)slo;
  return (o > k) ? o : k;
}

// u32 max-reduce across the wave (prefix to lane63 via DPP), broadcast via
// readlane(63). Identity 0.
__device__ __forceinline__ unsigned wave_umax_bcast(unsigned v) {
  unsigned o;
#define WSTEP(C)                                                              \
  o = (unsigned)__builtin_amdgcn_update_dpp(0, (int)v, C, 0xF, 0xF, true);    \
  v = (o > v) ? o : v;
  WSTEP(0x111)  // row_shr:1
  WSTEP(0x112)  // row_shr:2
  WSTEP(0x114)  // row_shr:4
  WSTEP(0x118)  // row_shr:8
  WSTEP(0x142)  // row_bcast:15
  WSTEP(0x143)  // row_bcast:31
#undef WSTEP
  return (unsigned)__builtin_amdgcn_readlane((int)v, 63);
}

__device__ __forceinline__ v2f emin2(v2f a, v2f b) {
  v2f r; r[0] = fminf(a[0], b[0]); r[1] = fminf(a[1], b[1]); return r;
}
__device__ __forceinline__ v2f emax2(v2f a, v2f b) {
  v2f r; r[0] = fmaxf(a[0], b[0]); r[1] = fmaxf(a[1], b[1]); return r;
}

// spread 4 bits: bit k -> bit 3k (for 12-bit Morton)
__device__ __forceinline__ unsigned spread4(unsigned v) {
  return (v & 1u) | ((v & 2u) << 2) | ((v & 4u) << 4) | ((v & 8u) << 6);
}

__device__ __forceinline__ unsigned cell_of(float x, float y, float z) {
  int cx = (int)floorf((x + 4.f) * 2.f);
  int cy = (int)floorf((y + 4.f) * 2.f);
  int cz = (int)floorf((z + 4.f) * 2.f);
  cx = min(max(cx, 0), 15); cy = min(max(cy, 0), 15); cz = min(max(cz, 0), 15);
  return spread4((unsigned)cx) | (spread4((unsigned)cy) << 1) |
         (spread4((unsigned)cz) << 2);
}

// ---------------------------------------------------------------------------
// Counting sort by 12-bit Morton cell -> spts float4 {x,y,z,bits(orig_idx)}.
// Also writes x4 = original-order float4 copy (aligned 16B winner-coord loads
// for fps). Within-cell scatter order is atomic-nondeterministic but the FPS
// output is invariant to it (keys carry original indices; skips are provable
// no-ops).
// ---------------------------------------------------------------------------
__global__ __launch_bounds__(1024) void sort_kernel(
    const float* __restrict__ xyz, float4* __restrict__ spts,
    float4* __restrict__ x4)
{
  const int b = blockIdx.x;
  const float* X = xyz + (size_t)b * NN * 3;
  float4* SP = spts + (size_t)b * NN;
  float4* XO = x4 + (size_t)b * NN;
  const int t = threadIdx.x;
  const int lane = t & 63, wid = t >> 6;

  __shared__ unsigned h[4096];
  __shared__ unsigned wtot[16];
  for (int j = t; j < 4096; j += 1024) h[j] = 0;
  __syncthreads();

  for (int i = 0; i < 16; ++i) {
    int p = i * 1024 + t;
    float x = X[p * 3 + 0], y = X[p * 3 + 1], z = X[p * 3 + 2];
    XO[p] = make_float4(x, y, z, 0.f);
    atomicAdd(&h[cell_of(x, y, z)], 1u);
  }
  __syncthreads();

  unsigned a0 = h[4 * t], a1 = h[4 * t + 1], a2 = h[4 * t + 2], a3 = h[4 * t + 3];
  unsigned s4 = a0 + a1 + a2 + a3;
  unsigned incl = s4;
  for (int off = 1; off < 64; off <<= 1) {
    unsigned v = (unsigned)__shfl_up((int)incl, off);
    if (lane >= off) incl += v;
  }
  if (lane == 63) wtot[wid] = incl;
  __syncthreads();
  if (t == 0) {
    unsigned run = 0;
    for (int j = 0; j < 16; ++j) { unsigned tm = wtot[j]; wtot[j] = run; run += tm; }
  }
  __syncthreads();
  unsigned ex = wtot[wid] + (incl - s4);
  h[4 * t] = ex; h[4 * t + 1] = ex + a0;
  h[4 * t + 2] = ex + a0 + a1; h[4 * t + 3] = ex + a0 + a1 + a2;
  __syncthreads();

  for (int i = 0; i < 16; ++i) {
    int p = i * 1024 + t;
    float x = X[p * 3 + 0], y = X[p * 3 + 1], z = X[p * 3 + 2];
    unsigned pos = atomicAdd(&h[cell_of(x, y, z)], 1u);
    SP[pos] = make_float4(x, y, z, __int_as_float(p));
  }
}

// ---------------------------------------------------------------------------
// FPS: 1024 threads / 16 waves, wave-granularity exact pruning (R5 structure,
// the best measured), with (a) packed-v2f distance updates (fp contract off:
// per-element rounding == scalar == numpy) and (b) a two-phase float-bits
// argmax replacing per-point u64 keys:
//   phase1: fmax tree + 6-step DPP u32 max -> wave max dist bits mm
//           (dist^2 >= 0 so bit order == float order)
//   phase2: (bits(d)==mm ? ~orig_idx : 0) tree + 6-step DPP u32 max -> winner
//           (max ~idx == min orig idx == numpy first-index tie-break)
// Cross-wave: cached (mm,~idx) key per wave in LDS (double-buffered, always
// republished, ONE barrier), u64 DPP ror reduce, winner coords re-loaded as
// one dwordx4 from the original-order float4 copy.
// Skips are provably no-op fmin updates (margin 1-2^-16 covers both our and
// the reference's rounding). Output invariant to sort nondeterminism.
// ---------------------------------------------------------------------------
__global__ __launch_bounds__(1024) void fps_kernel(
    const float4* __restrict__ x4, const float4* __restrict__ spts,
    float* __restrict__ new_xyz)
{
#pragma clang fp contract(off)
  const int b = blockIdx.x;
  const float4* XO = x4 + (size_t)b * NN;
  float* NX = new_xyz + (size_t)b * SS * 3;
  const int t = threadIdx.x;
  const int lane = t & 63, wid = t >> 6;
  const float4* WP = spts + (size_t)b * NN + wid * 1024;

  v2f xp0, xp1, xp2, xp3, xp4, xp5, xp6, xp7;
  v2f yp0, yp1, yp2, yp3, yp4, yp5, yp6, yp7;
  v2f zp0, zp1, zp2, zp3, zp4, zp5, zp6, zp7;
  v2f dp0, dp1, dp2, dp3, dp4, dp5, dp6, dp7;
  unsigned na0, na1, na2, na3, na4, na5, na6, na7;
  unsigned nb0, nb1, nb2, nb3, nb4, nb5, nb6, nb7;
#define LOADV(v)                                                              \
  {                                                                           \
    float4 Pa = WP[(2 * (v)) * 64 + lane];                                    \
    float4 Pb = WP[(2 * (v) + 1) * 64 + lane];                                \
    xp##v[0] = Pa.x; xp##v[1] = Pb.x;                                         \
    yp##v[0] = Pa.y; yp##v[1] = Pb.y;                                         \
    zp##v[0] = Pa.z; zp##v[1] = Pb.z;                                         \
    na##v = ~__float_as_uint(Pa.w); nb##v = ~__float_as_uint(Pb.w);           \
    dp##v[0] = 1e10f; dp##v[1] = 1e10f;                                       \
  }
  LOADV(0) LOADV(1) LOADV(2) LOADV(3) LOADV(4) LOADV(5) LOADV(6) LOADV(7)
#undef LOADV

  // wave bbox (uniform across the wave after shuffles)
  float bnx, bny, bnz, bxx, bxy, bxz;
  {
    v2f nx2 = emin2(emin2(emin2(xp0, xp1), emin2(xp2, xp3)),
                    emin2(emin2(xp4, xp5), emin2(xp6, xp7)));
    v2f xx2 = emax2(emax2(emax2(xp0, xp1), emax2(xp2, xp3)),
                    emax2(emax2(xp4, xp5), emax2(xp6, xp7)));
    v2f ny2 = emin2(emin2(emin2(yp0, yp1), emin2(yp2, yp3)),
                    emin2(emin2(yp4, yp5), emin2(yp6, yp7)));
    v2f xy2 = emax2(emax2(emax2(yp0, yp1), emax2(yp2, yp3)),
                    emax2(emax2(yp4, yp5), emax2(yp6, yp7)));
    v2f nz2 = emin2(emin2(emin2(zp0, zp1), emin2(zp2, zp3)),
                    emin2(emin2(zp4, zp5), emin2(zp6, zp7)));
    v2f xz2 = emax2(emax2(emax2(zp0, zp1), emax2(zp2, zp3)),
                    emax2(emax2(zp4, zp5), emax2(zp6, zp7)));
    bnx = fminf(nx2[0], nx2[1]); bxx = fmaxf(xx2[0], xx2[1]);
    bny = fminf(ny2[0], ny2[1]); bxy = fmaxf(xy2[0], xy2[1]);
    bnz = fminf(nz2[0], nz2[1]); bxz = fmaxf(xz2[0], xz2[1]);
#pragma unroll
    for (int off = 1; off < 64; off <<= 1) {
      bnx = fminf(bnx, __shfl_xor(bnx, off));
      bxx = fmaxf(bxx, __shfl_xor(bxx, off));
      bny = fminf(bny, __shfl_xor(bny, off));
      bxy = fmaxf(bxy, __shfl_xor(bxy, off));
      bnz = fminf(bnz, __shfl_xor(bnz, off));
      bxz = fmaxf(bxz, __shfl_xor(bxz, off));
    }
  }

  // cached wave key: max dist bits + ~orig_idx of the wave winner
  unsigned wmaxb = __float_as_uint(1e10f), wni = 0u;

  __shared__ u64 sp[2][16];
  float qx, qy, qz;
  { float4 q0 = XO[0]; qx = q0.x; qy = q0.y; qz = q0.z; }

  for (int it = 1; it < SS; ++it) {
    if (t == 0) {
      NX[(it - 1) * 3 + 0] = qx;
      NX[(it - 1) * 3 + 1] = qy;
      NX[(it - 1) * 3 + 2] = qz;
    }
    // conservative lower bound of dist^2(q, wave bbox); wave-uniform branch
    float tx = fmaxf(fmaxf(__fsub_rn(bnx, qx), __fsub_rn(qx, bxx)), 0.f);
    float ty = fmaxf(fmaxf(__fsub_rn(bny, qy), __fsub_rn(qy, bxy)), 0.f);
    float tz = fmaxf(fmaxf(__fsub_rn(bnz, qz), __fsub_rn(qz, bxz)), 0.f);
    float lb2 = fmaf(tx, tx, fmaf(ty, ty, __fmul_rn(tz, tz)));
    if (__fmul_rn(lb2, 0.99998474f) < __uint_as_float(wmaxb)) {
      v2f q2x, q2y, q2z;
      q2x[0] = qx; q2x[1] = qx;
      q2y[0] = qy; q2y[1] = qy;
      q2z[0] = qz; q2z[1] = qz;
#define UPDV(v)                                                               \
      {                                                                       \
        v2f dx = xp##v - q2x, dy = yp##v - q2y, dz = zp##v - q2z;             \
        v2f s = (dx * dx + dy * dy) + dz * dz;                                \
        dp##v = emin2(dp##v, s);                                              \
      }
      UPDV(0) UPDV(1) UPDV(2) UPDV(3) UPDV(4) UPDV(5) UPDV(6) UPDV(7)
#undef UPDV
      // phase 1: wave max dist (float-bit order == float order, dist >= 0)
      v2f mall = emax2(emax2(emax2(dp0, dp1), emax2(dp2, dp3)),
                       emax2(emax2(dp4, dp5), emax2(dp6, dp7)));
      unsigned mm = wave_umax_bcast(__float_as_uint(fmaxf(mall[0], mall[1])));
      // phase 2: tie-exact winner extraction (max ~idx == min orig idx)
      unsigned c = 0u;
#define CSEL(v)                                                               \
      c = max(c, (__float_as_uint(dp##v[0]) == mm) ? na##v : 0u);             \
      c = max(c, (__float_as_uint(dp##v[1]) == mm) ? nb##v : 0u);
      CSEL(0) CSEL(1) CSEL(2) CSEL(3) CSEL(4) CSEL(5) CSEL(6) CSEL(7)
#undef CSEL
      wni = wave_umax_bcast(c);
      wmaxb = mm;
    }
    // publish cached key (always; double-buffered, single barrier)
    const int pb = it & 1;
    if (lane == 0) sp[pb][wid] = ((u64)wmaxb << 32) | (u64)wni;
    __syncthreads();
    u64 kk = sp[pb][lane & 15];
    kk = dpp_max_step<0x128>(kk);  // row_ror:8
    kk = dpp_max_step<0x124>(kk);  // row_ror:4
    kk = dpp_max_step<0x122>(kk);  // row_ror:2
    kk = dpp_max_step<0x121>(kk);  // row_ror:1
    unsigned widx = ~(unsigned)(kk & 0xffffffffull);
    widx = (unsigned)__builtin_amdgcn_readfirstlane((int)widx);
    float4 q = XO[widx];
    qx = q.x; qy = q.y; qz = q.z;
  }
  if (t == 0) {
    NX[(SS - 1) * 3 + 0] = qx;
    NX[(SS - 1) * 3 + 1] = qy;
    NX[(SS - 1) * 3 + 2] = qz;
  }
}

// ---------------------------------------------------------------------------
// Ball query: one 64-lane wave per query point. Emits the first NS in-radius
// point indices in ascending order (matches reference top_k(-keys) trick),
// pads with the first hit.
// ---------------------------------------------------------------------------
template <int NS>
__global__ __launch_bounds__(256) void ballq_kernel(
    const float* __restrict__ xyz, const float* __restrict__ new_xyz,
    int* __restrict__ out, float r2)
{
  const int q = blockIdx.x * 4 + (threadIdx.x >> 6);
  const int lane = threadIdx.x & 63;
  const int b = q >> 12;  // q / SS
  const float* X = xyz + (size_t)b * NN * 3;
  const float cx = new_xyz[q * 3 + 0];
  const float cy = new_xyz[q * 3 + 1];
  const float cz = new_xyz[q * 3 + 2];
  int* o = out + (size_t)q * NS;
  int base = 0;
  int firstIdx = 0x7fffffff;
  for (int c0 = 0; c0 < NN; c0 += 64) {
    const int p = c0 + lane;
    float dx = __fsub_rn(cx, X[p * 3 + 0]);
    float dy = __fsub_rn(cy, X[p * 3 + 1]);
    float dz = __fsub_rn(cz, X[p * 3 + 2]);
    float d2 = __fadd_rn(__fadd_rn(__fmul_rn(dx, dx), __fmul_rn(dy, dy)),
                         __fmul_rn(dz, dz));
    const bool inb = d2 < r2;
    const unsigned long long mm = __ballot(inb);
    if (inb) {
      int rank = base + (int)__popcll(mm & ((1ull << lane) - 1ull));
      if (rank < NS) {
        o[rank] = p;
        if (rank == 0) firstIdx = p;
      }
    }
    base += (int)__popcll(mm);
    if (base >= NS) break;
  }
#pragma unroll
  for (int off = 32; off >= 1; off >>= 1)
    firstIdx = min(firstIdx, __shfl_xor(firstIdx, off));
  for (int r = base + lane; r < NS; r += 64) o[r] = firstIdx;
}

// ---------------------------------------------------------------------------
// Grouping + 3-layer MLP + max over samples. One thread per (query, sample).
// ---------------------------------------------------------------------------
template <int NS, int C1, int C2, int C3>
__global__ __launch_bounds__(256) void group_mlp_kernel(
    const float* __restrict__ xyz, const float* __restrict__ feat,
    const float* __restrict__ new_xyz, const int* __restrict__ idx,
    const float* __restrict__ w0, const float* __restrict__ b0,
    const float* __restrict__ w1, const float* __restrict__ b1,
    const float* __restrict__ w2, const float* __restrict__ b2,
    float* __restrict__ pf, int chOff)
{
  constexpr int QPB = 256 / NS;
  const int q = blockIdx.x * QPB + (int)(threadIdx.x / NS);
  const int k = (int)(threadIdx.x % NS);
  const int b = q >> 12;
  const int s = q & (SS - 1);
  const float* X = xyz + (size_t)b * NN * 3;
  const float* F = feat + (size_t)b * 6 * NN;
  const int p = idx[(size_t)q * NS + k];

  float in[9];
  in[0] = X[p * 3 + 0] - new_xyz[q * 3 + 0];
  in[1] = X[p * 3 + 1] - new_xyz[q * 3 + 1];
  in[2] = X[p * 3 + 2] - new_xyz[q * 3 + 2];
#pragma unroll
  for (int c = 0; c < 6; ++c) in[3 + c] = F[c * NN + p];

  float h1[C1];
#pragma unroll
  for (int oc = 0; oc < C1; ++oc) {
    float a = b0[oc];
#pragma unroll
    for (int c = 0; c < 9; ++c) a = fmaf(w0[oc * 9 + c], in[c], a);
    h1[oc] = fmaxf(a, 0.f);
  }
  float h2[C2];
#pragma unroll
  for (int oc = 0; oc < C2; ++oc) {
    float a = b1[oc];
#pragma unroll
    for (int c = 0; c < C1; ++c) a = fmaf(w1[oc * C1 + c], h1[c], a);
    h2[oc] = fmaxf(a, 0.f);
  }
#pragma unroll
  for (int oc = 0; oc < C3; ++oc) {
    float a = b2[oc];
#pragma unroll
    for (int c = 0; c < C2; ++c) a = fmaf(w2[oc * C2 + c], h2[c], a);
    float v = fmaxf(a, 0.f);
#pragma unroll
    for (int off = NS / 2; off >= 1; off >>= 1)
      v = fmaxf(v, __shfl_xor(v, off));
    if (k == 0) pf[(((size_t)b * 96) + chOff + oc) * SS + s] = v;
  }
}

// ---------------------------------------------------------------------------
// Image branch + attention + fusion, 32-column LDS tiles.
// ---------------------------------------------------------------------------
__global__ __launch_bounds__(256) void img_fuse_kernel(
    const float* __restrict__ imgf, const float* __restrict__ pf,
    const float* __restrict__ w_img, const float* __restrict__ b_img,
    const float* __restrict__ w_fc2, const float* __restrict__ b_fc2,
    const float* __restrict__ w_fc3, const float* __restrict__ b_fc3,
    const float* __restrict__ w_pc, const float* __restrict__ b_pc,
    const float* __restrict__ w_fuse, const float* __restrict__ b_fuse,
    float* __restrict__ out)
{
  constexpr int TS = 32;
  __shared__ float x_lds[64][TS];
  __shared__ float img_lds[96][TS];
  __shared__ float ri_lds[24][TS];
  __shared__ float att_lds[TS];
  __shared__ float imgn_lds[96][TS];
  __shared__ float pf_lds[96][TS];

  const int blk = blockIdx.x;            // B * (SS/TS) = 256 blocks
  const int b = blk / (SS / TS);
  const int s0 = (blk % (SS / TS)) * TS;
  const int tid = threadIdx.x;

  for (int i = tid; i < 64 * TS; i += 256) {
    int c = i / TS, s = i % TS;
    x_lds[c][s] = imgf[((size_t)b * 64 + c) * SS + s0 + s];
  }
  for (int i = tid; i < 96 * TS; i += 256) {
    int c = i / TS, s = i % TS;
    pf_lds[c][s] = pf[((size_t)b * 96 + c) * SS + s0 + s];
  }
  __syncthreads();

  for (int i = tid; i < 96 * TS; i += 256) {
    int oc = i / TS, s = i % TS;
    float a = b_img[oc];
#pragma unroll
    for (int c = 0; c < 64; ++c) a = fmaf(w_img[oc * 64 + c], x_lds[c][s], a);
    img_lds[oc][s] = fmaxf(a, 0.f);
  }
  __syncthreads();

  for (int i = tid; i < 24 * TS; i += 256) {
    int r = i / TS, s = i % TS;
    float a = b_fc2[r];
#pragma unroll
    for (int c = 0; c < 96; ++c) a = fmaf(w_fc2[r * 96 + c], img_lds[c][s], a);
    ri_lds[r][s] = tanhf(a);
  }
  __syncthreads();

  if (tid < TS) {
    float a = b_fc3[0];
#pragma unroll
    for (int r = 0; r < 24; ++r) a = fmaf(w_fc3[r], ri_lds[r][tid], a);
    att_lds[tid] = 1.f / (1.f + expf(-a));
  }
  __syncthreads();

  for (int i = tid; i < 96 * TS; i += 256) {
    int c = i / TS, s = i % TS;
    float v = img_lds[c][s];
    img_lds[c][s] = fmaf(v, att_lds[s], v);
  }
  __syncthreads();

  for (int i = tid; i < 96 * TS; i += 256) {
    int oc = i / TS, s = i % TS;
    float a = b_pc[oc];
#pragma unroll
    for (int c = 0; c < 96; ++c) a = fmaf(w_pc[oc * 96 + c], img_lds[c][s], a);
    imgn_lds[oc][s] = fmaxf(a, 0.f);
  }
  __syncthreads();

  for (int i = tid; i < 128 * TS; i += 256) {
    int oc = i / TS, s = i % TS;
    float a = b_fuse[oc];
#pragma unroll
    for (int c = 0; c < 96; ++c) a = fmaf(w_fuse[oc * 192 + c], pf_lds[c][s], a);
#pragma unroll
    for (int c = 0; c < 96; ++c) a = fmaf(w_fuse[oc * 192 + 96 + c], imgn_lds[c][s], a);
    out[((size_t)b * 128 + oc) * SS + s0 + s] = fmaxf(a, 0.f);
  }
}

// ---------------------------------------------------------------------------
extern "C" void kernel_launch(void* const* d_in, const int* in_sizes, int n_in,
                              void* d_out, int out_size, void* d_ws, size_t ws_size,
                              hipStream_t stream)
{
  const float* xyz    = (const float*)d_in[0];
  const float* feat   = (const float*)d_in[1];
  const float* imgf   = (const float*)d_in[2];
  const float* w0_0   = (const float*)d_in[3];
  const float* b0_0   = (const float*)d_in[4];
  const float* w0_1   = (const float*)d_in[5];
  const float* b0_1   = (const float*)d_in[6];
  const float* w0_2   = (const float*)d_in[7];
  const float* b0_2   = (const float*)d_in[8];
  const float* w1_0   = (const float*)d_in[9];
  const float* b1_0   = (const float*)d_in[10];
  const float* w1_1   = (const float*)d_in[11];
  const float* b1_1   = (const float*)d_in[12];
  const float* w1_2   = (const float*)d_in[13];
  const float* b1_2   = (const float*)d_in[14];
  const float* w_img  = (const float*)d_in[15];
  const float* b_img  = (const float*)d_in[16];
  const float* w_fc2  = (const float*)d_in[17];
  const float* b_fc2  = (const float*)d_in[18];
  const float* w_fc3  = (const float*)d_in[19];
  const float* b_fc3  = (const float*)d_in[20];
  const float* w_pc   = (const float*)d_in[21];
  const float* b_pc   = (const float*)d_in[22];
  const float* w_fuse = (const float*)d_in[23];
  const float* b_fuse = (const float*)d_in[24];
  float* out = (float*)d_out;

  float4* spts = (float4*)d_ws;                          // B*N float4
  float4* x4   = spts + (size_t)BB * NN;                 // B*N float4
  float*  nxyz = (float*)(x4 + (size_t)BB * NN);         // B*S*3 f32
  int*    idx0 = (int*)(nxyz + (size_t)BB * SS * 3);     // B*S*16 i32
  int*    idx1 = idx0 + (size_t)BB * SS * 16;            // B*S*32 i32
  float*  pf   = (float*)(idx1 + (size_t)BB * SS * 32);  // B*96*S f32

  sort_kernel<<<BB, 1024, 0, stream>>>(xyz, spts, x4);
  fps_kernel<<<BB, 1024, 0, stream>>>(x4, spts, nxyz);
  ballq_kernel<16><<<BB * SS / 4, 256, 0, stream>>>(xyz, nxyz, idx0, 0.25f);
  ballq_kernel<32><<<BB * SS / 4, 256, 0, stream>>>(xyz, nxyz, idx1, 1.0f);
  group_mlp_kernel<16, 16, 16, 32><<<BB * SS / 16, 256, 0, stream>>>(
      xyz, feat, nxyz, idx0, w0_0, b0_0, w0_1, b0_1, w0_2, b0_2, pf, 0);
  group_mlp_kernel<32, 32, 32, 64><<<BB * SS / 8, 256, 0, stream>>>(
      xyz, feat, nxyz, idx1, w1_0, b1_0, w1_1, b1_1, w1_2, b1_2, pf, 32);
  img_fuse_kernel<<<BB * SS / 32, 256, 0, stream>>>(
      imgf, pf, w_img, b_img, w_fc2, b_fc2, w_fc3, b_fc3, w_pc, b_pc,
      w_fuse, b_fuse, out);
}